// Round 2
// baseline (263.230 us; speedup 1.0000x reference)
//
#include <hip/hip_runtime.h>
#include <math.h>

// DCT encoder, separable form. kernels[k] = outer(cv_k, cu_k) with
// cv[i]=cos((2i+1)v pi/64) on ROWS (i), cu[j] on COLUMNS (j)  [meshgrid 'xy'].
// Stage1 contracts y=cols with freq f1==u; stage2 contracts x=rows with f2==v.
// R6: read-once + full wave occupancy. One block per (b,m) strip, 1024 threads
// (16 waves): 2 blocks/CU x 16 waves = 32 waves/CU, ALL 512 blocks co-resident
// (zero tail, m-pair stores phase-aligned). RGB loaded ONCE per strip (100 MB
// logical reads, was 302 MB in R5's channel-split), all 3 channels converted to
// registers, then pushed through the 40 KB LDS T buffer channel-by-channel.
// T2 reordered so stage-2 threads prefetch their 8 {k,scale} entries as 4x16B.

typedef __bf16 bf16x8 __attribute__((ext_vector_type(8)));
typedef float  f32x4  __attribute__((ext_vector_type(4)));

#define PI_F 3.14159265358979323846f

__device__ __forceinline__ unsigned short f2bf(float f) {
    union { float f; unsigned u; } v; v.f = f;
    unsigned u = v.u;
    u += 0x7fffu + ((u >> 16) & 1u);   // round-to-nearest-even
    return (unsigned short)(u >> 16);
}

// ---- K0: cos table (bf16) + fused {k, scale} table --------------------------
// kern[k][i][j] = cos((2j+1)u pi/64) * cos((2i+1)v pi/64), k sorted by |(v,u)|.
// v from K[1][0]/K[0][0] = 4cos^2(v pi/64)-3; u from K[0][1]/K[0][0].
// T2r layout: [(u*4 + quad)*8 + uh*4 + r] where v = uh*16 + quad*4 + r,
// so stage-2's (f1=u, quad) thread reads its 8 entries as one 64B run.
__global__ __launch_bounds__(256) void setup_kernel(const float* __restrict__ kern,
                                                    const float* __restrict__ factors,
                                                    unsigned short* __restrict__ Cbf,
                                                    int2* __restrict__ T2) {
    int k = blockIdx.x * 256 + threadIdx.x;   // 0..1023
    int i = k & 31, t = k >> 5;
    Cbf[k] = f2bf(cosf((float)((2 * i + 1) * t) * (PI_F / 64.f)));

    float k00 = kern[(size_t)k * 1024];              // cv[0]*cu[0] > 0 always
    float rv  = kern[(size_t)k * 1024 + 32] / k00;   // -> v
    float ru  = kern[(size_t)k * 1024 + 1]  / k00;   // -> u
    float cv2 = fminf(fmaxf((rv + 3.f) * 0.25f, 0.f), 1.f);
    float cu2 = fminf(fmaxf((ru + 3.f) * 0.25f, 0.f), 1.f);
    int v = __float2int_rn(acosf(sqrtf(cv2)) * (64.f / PI_F));
    int u = __float2int_rn(acosf(sqrtf(cu2)) * (64.f / PI_F));
    float s = factors[k] * (2.f / 32.f);
    int vq = (v >> 2) & 3, vh = v >> 4, vr = v & 3;
    T2[(u * 4 + vq) * 8 + vh * 4 + vr] = make_int2(k, __float_as_int(s));
}

// ---- fused kernel: one block per (b, m) strip of 16 DCT blocks --------------
// 1024 threads = 16 waves; wave w owns x-rows {2w, 2w+1} (stage 1) and
// f1 in {2w, 2w+1} (stage 2). 3 channels sequential through one LDS T buffer.
// Stage1: T[f1][n][x] = sum_y C[f1][y] * ycbcr[c][m*32+x][n*32+y]   (MFMA, K=32)
// Stage2: out[bc][k(f2,f1)][m*16+n] = s * sum_x C[f2][x] * T[f1][n][x]
// LDS T row (f1,n): 80 B (32 bf16 + 16 pad), f1-stride 1280 B -> 40 KB.
__global__ __launch_bounds__(1024, 8) void dct_fused(const float* __restrict__ rgb,
                                                     const unsigned short* __restrict__ Cbf,
                                                     const int2* __restrict__ T2,
                                                     float* __restrict__ out) {
    __shared__ __align__(16) unsigned char Tls[32 * 1280];   // 40 KB

    const int tid  = threadIdx.x;
    const int lane = tid & 63;
    const int w    = tid >> 6;        // wave 0..15
    const int quad = lane >> 4;
    const int l15  = lane & 15;
    // g<->g+8 pair swizzle: m=2t / 2t+1 blocks land on the same XCD (%8
    // round-robin) so their half-128B output lines merge in that XCD's L2.
    const int g    = blockIdx.x;      // 0..511
    const int b    = g >> 4;
    const int loc  = g & 15;
    const int m    = ((loc & 7) << 1) | (loc >> 3);

    // A-operand frags (both stages): A[row=l15][k=quad*8+j] = C[row][pos]
    union { bf16x8 v; unsigned short s[8]; } af0, af1;
    af0.v = *(const bf16x8*)(Cbf + l15 * 32 + quad * 8);
    af1.v = *(const bf16x8*)(Cbf + (16 + l15) * 32 + quad * 8);

    const f32x4 zero = {0.f, 0.f, 0.f, 0.f};

    // ---- stage 1a: load rgb ONCE, convert all 3 channels (12 VGPR of frags) --
    bf16x8 fr[3][2];   // [c][xi]
    const float* rbase = rgb + (size_t)b * 786432 + (size_t)l15 * 32 + (size_t)quad * 8;
#pragma unroll
    for (int xi = 0; xi < 2; ++xi) {
        const int x = w * 2 + xi;
        const float* p = rbase + (size_t)(m * 32 + x) * 512;
        float4 R0 = *(const float4*)(p);
        float4 R1 = *(const float4*)(p + 4);
        float4 G0 = *(const float4*)(p + 262144);
        float4 G1 = *(const float4*)(p + 262148);
        float4 B0 = *(const float4*)(p + 524288);
        float4 B1 = *(const float4*)(p + 524292);
        float R[8]  = {R0.x, R0.y, R0.z, R0.w, R1.x, R1.y, R1.z, R1.w};
        float G[8]  = {G0.x, G0.y, G0.z, G0.w, G1.x, G1.y, G1.z, G1.w};
        float Bv[8] = {B0.x, B0.y, B0.z, B0.w, B1.x, B1.y, B1.z, B1.w};
        union { bf16x8 v; unsigned short s[8]; } fy, fcb, fcr;
#pragma unroll
        for (int e = 0; e < 8; ++e) {
            float y = 0.299f * R[e] + 0.587f * G[e] + 0.114f * Bv[e];
            fy.s[e]  = f2bf(2.f * y - 1.f);           // 2*Y - 1
            fcb.s[e] = f2bf(1.128f * (Bv[e] - y));    // 2*((b-y)*.564+.5) - 1
            fcr.s[e] = f2bf(1.426f * (R[e] - y));     // 2*((r-y)*.713+.5) - 1
        }
        fr[0][xi] = fy.v;
        fr[1][xi] = fcb.v;
        fr[2][xi] = fcr.v;
    }

    // ---- per channel: stage-1 MFMAs -> LDS -> stage 2 ----
    const size_t obase0 = (size_t)(b * 3) * 262144 + (size_t)m * 16 + (size_t)l15;
#pragma unroll
    for (int c = 0; c < 3; ++c) {
#pragma unroll
        for (int fh = 0; fh < 2; ++fh) {
            f32x4 dd[2];
#pragma unroll
            for (int xi = 0; xi < 2; ++xi)
                dd[xi] = __builtin_amdgcn_mfma_f32_16x16x32_bf16(
                    fh ? af1.v : af0.v, fr[c][xi], zero, 0, 0, 0);
            // scatter: T[f1][n=l15][x-pair w], rows f1 = fh*16+quad*4+r
#pragma unroll
            for (int r = 0; r < 4; ++r) {
                const int f1 = fh * 16 + quad * 4 + r;
                ushort2 pk;
                pk.x = f2bf(dd[0][r]);
                pk.y = f2bf(dd[1][r]);
                *(ushort2*)(Tls + f1 * 1280 + l15 * 80 + w * 4) = pk;
            }
        }
        __syncthreads();

        const size_t obase = obase0 + (size_t)c * 262144;
#pragma unroll
        for (int i = 0; i < 2; ++i) {
            const int f1 = w * 2 + i;   // stage-1 freq == u (column freq)
            union { int4 q[4]; int2 e[8]; } tt;
            const int4* tp = (const int4*)(T2 + ((f1 * 4 + quad) << 3));
            tt.q[0] = tp[0]; tt.q[1] = tp[1]; tt.q[2] = tp[2]; tt.q[3] = tp[3];
            bf16x8 bfr = *(const bf16x8*)(Tls + f1 * 1280 + l15 * 80 + quad * 16);
#pragma unroll
            for (int uh = 0; uh < 2; ++uh) {
                f32x4 d2 = __builtin_amdgcn_mfma_f32_16x16x32_bf16(
                    uh ? af1.v : af0.v, bfr, zero, 0, 0, 0);
#pragma unroll
                for (int r = 0; r < 4; ++r) {
                    int2 ks = tt.e[uh * 4 + r];   // {k, scale} for f2 = uh*16+quad*4+r
                    out[obase + (size_t)ks.x * 256] = d2[r] * __int_as_float(ks.y);
                }
            }
        }
        if (c < 2) __syncthreads();   // T reads done before next channel overwrites
    }
}

extern "C" void kernel_launch(void* const* d_in, const int* in_sizes, int n_in,
                              void* d_out, int out_size, void* d_ws, size_t ws_size,
                              hipStream_t stream) {
    const float* rgb     = (const float*)d_in[0];  // (32,3,512,512)
    const float* kern    = (const float*)d_in[1];  // (1024,32,32)
    const float* factors = (const float*)d_in[2];  // (1024,)
    float* out = (float*)d_out;                    // (32,3072,16,16)

    unsigned short* Cbf = (unsigned short*)d_ws;          // 2 KB
    int2* T2 = (int2*)((char*)d_ws + 8192);               // 8 KB

    setup_kernel<<<4, 256, 0, stream>>>(kern, factors, Cbf, T2);
    dct_fused<<<512, 1024, 0, stream>>>(rgb, Cbf, T2, out);
}

// Round 3
// 210.363 us; speedup vs baseline: 1.2513x; 1.2513x over previous
//
#include <hip/hip_runtime.h>
#include <math.h>

// DCT encoder, separable form. kernels[k] = outer(cv_k, cu_k) with
// cv[i]=cos((2i+1)v pi/64) on ROWS (i), cu[j] on COLUMNS (j)  [meshgrid 'xy'].
// Stage1 contracts y=cols with freq f1==u; stage2 contracts x=rows with f2==v.
// R7 = R5 (channel-split, the only structure with ideal WRITE=103MB) plus:
//  - __launch_bounds__(512,6): VGPR cap 85 (was 64, compiler used 32 ->
//    load phase serialized into ~8 dependent round-trips). 3 blocks/CU ->
//    1536 blocks = exactly 2 full residency rounds, zero tail.
//  - stage-1a restructured into plane passes (R, then G, then B): 8 float4
//    loads issued back-to-back per plane, FMA pass overlaps next plane's
//    loads. Peak live regs ~82, fits the cap without spill.
// Store pattern / T2 prefetch / LDS layout byte-identical to R5.

typedef __bf16 bf16x8 __attribute__((ext_vector_type(8)));
typedef float  f32x4  __attribute__((ext_vector_type(4)));

#define PI_F 3.14159265358979323846f

__device__ __forceinline__ unsigned short f2bf(float f) {
    union { float f; unsigned u; } v; v.f = f;
    unsigned u = v.u;
    u += 0x7fffu + ((u >> 16) & 1u);   // round-to-nearest-even
    return (unsigned short)(u >> 16);
}

// ---- K0: cos table (bf16) + fused {k, scale} table --------------------------
// kern[k][i][j] = cos((2j+1)u pi/64) * cos((2i+1)v pi/64), k sorted by |(v,u)|.
// v from K[1][0]/K[0][0] = 4cos^2(v pi/64)-3; u from K[0][1]/K[0][0].
// T2r layout: [(u*4 + quad)*8 + uh*4 + r] where v = uh*16 + quad*4 + r,
// so stage-2's (f1=u, quad) thread reads its 8 entries as one 64B run.
__global__ __launch_bounds__(256) void setup_kernel(const float* __restrict__ kern,
                                                    const float* __restrict__ factors,
                                                    unsigned short* __restrict__ Cbf,
                                                    int2* __restrict__ T2) {
    int k = blockIdx.x * 256 + threadIdx.x;   // 0..1023
    int i = k & 31, t = k >> 5;
    Cbf[k] = f2bf(cosf((float)((2 * i + 1) * t) * (PI_F / 64.f)));

    float k00 = kern[(size_t)k * 1024];              // cv[0]*cu[0] > 0 always
    float rv  = kern[(size_t)k * 1024 + 32] / k00;   // -> v
    float ru  = kern[(size_t)k * 1024 + 1]  / k00;   // -> u
    float cv2 = fminf(fmaxf((rv + 3.f) * 0.25f, 0.f), 1.f);
    float cu2 = fminf(fmaxf((ru + 3.f) * 0.25f, 0.f), 1.f);
    int v = __float2int_rn(acosf(sqrtf(cv2)) * (64.f / PI_F));
    int u = __float2int_rn(acosf(sqrtf(cu2)) * (64.f / PI_F));
    float s = factors[k] * (2.f / 32.f);
    int vq = (v >> 2) & 3, vh = v >> 4, vr = v & 3;
    T2[(u * 4 + vq) * 8 + vh * 4 + vr] = make_int2(k, __float_as_int(s));
}

// ---- fused kernel: one block per (b, m, c) strip of 16 DCT blocks -----------
// Stage1: T[f1][n][x] = sum_y C[f1][y] * ycbcr[c][m*32+x][n*32+y]   (MFMA, K=32)
// Stage2: out[bc][k(f2,f1)][m*16+n] = s * sum_x C[f2][x] * T[f1][n][x]
// LDS T row (f1,n): 80 B (32 bf16 + 16 pad), f1-stride 1280 B -> 40 KB.
__global__ __launch_bounds__(512, 6) void dct_fused(const float* __restrict__ rgb,
                                                    const unsigned short* __restrict__ Cbf,
                                                    const int2* __restrict__ T2,
                                                    float* __restrict__ out) {
    __shared__ __align__(16) unsigned char Tls[32 * 1280];   // 40 KB

    const int tid  = threadIdx.x;
    const int lane = tid & 63;
    const int w    = tid >> 6;        // wave 0..7, owns x = w*4..w*4+3
    const int quad = lane >> 4;
    const int l15  = lane & 15;
    // blockIdx decode: g = bc*16 + loc, bc = b*3 + c (c at stride 16 -> same XCD
    // for a strip's 3 channel-blocks), loc -> m with the g<->g+8 pair swizzle
    // so m=2t / 2t+1 half-lines merge to one 128B line in that XCD's L2.
    const int g    = blockIdx.x;
    const int bc   = g >> 4;          // 0..95
    const int b    = bc / 3;
    const int c    = bc - b * 3;
    const int loc  = g & 15;
    const int m    = ((loc & 7) << 1) | (loc >> 3);

    // channel conversion folded to one dot product: val = ar*R + ag*G + ab*B + ao
    // c=0: 2*(.299R+.587G+.114B)-1
    // c=1: 1.128*(B - Y)   c=2: 1.426*(R - Y)
    float ar, ag, ab, ao;
    if (c == 0)      { ar =  0.598f;     ag =  1.174f;     ab =  0.228f;     ao = -1.f; }
    else if (c == 1) { ar = -0.337272f;  ag = -0.662136f;  ab =  0.999408f;  ao =  0.f; }
    else             { ar =  0.999626f;  ag = -0.837062f;  ab = -0.162564f;  ao =  0.f; }

    // ---- stage 1a: plane-pass load + convert -------------------------------
    // This thread's 32 input elems: rows x = w*4+xi (xi=0..3), cols l15*32+quad*8+e.
    const float* prow = rgb + (size_t)b * 786432
                            + (size_t)(m * 32 + w * 4) * 512
                            + (size_t)l15 * 32 + (size_t)quad * 8;
    f32x4 acc[4][2];     // [xi][half] running ar*R+ag*G+ab*B
    {
        float4 buf[4][2];
        // R plane: issue all 8 loads, then FMA pass
#pragma unroll
        for (int xi = 0; xi < 4; ++xi) {
            buf[xi][0] = *(const float4*)(prow + (size_t)xi * 512);
            buf[xi][1] = *(const float4*)(prow + (size_t)xi * 512 + 4);
        }
#pragma unroll
        for (int xi = 0; xi < 4; ++xi)
            for (int h = 0; h < 2; ++h) {
                acc[xi][h][0] = ar * buf[xi][h].x;
                acc[xi][h][1] = ar * buf[xi][h].y;
                acc[xi][h][2] = ar * buf[xi][h].z;
                acc[xi][h][3] = ar * buf[xi][h].w;
            }
        // G plane
#pragma unroll
        for (int xi = 0; xi < 4; ++xi) {
            buf[xi][0] = *(const float4*)(prow + 262144 + (size_t)xi * 512);
            buf[xi][1] = *(const float4*)(prow + 262144 + (size_t)xi * 512 + 4);
        }
#pragma unroll
        for (int xi = 0; xi < 4; ++xi)
            for (int h = 0; h < 2; ++h) {
                acc[xi][h][0] += ag * buf[xi][h].x;
                acc[xi][h][1] += ag * buf[xi][h].y;
                acc[xi][h][2] += ag * buf[xi][h].z;
                acc[xi][h][3] += ag * buf[xi][h].w;
            }
        // B plane
#pragma unroll
        for (int xi = 0; xi < 4; ++xi) {
            buf[xi][0] = *(const float4*)(prow + 524288 + (size_t)xi * 512);
            buf[xi][1] = *(const float4*)(prow + 524288 + (size_t)xi * 512 + 4);
        }
#pragma unroll
        for (int xi = 0; xi < 4; ++xi)
            for (int h = 0; h < 2; ++h) {
                acc[xi][h][0] += ab * buf[xi][h].x;
                acc[xi][h][1] += ab * buf[xi][h].y;
                acc[xi][h][2] += ab * buf[xi][h].z;
                acc[xi][h][3] += ab * buf[xi][h].w;
            }
    }
    // pack to bf16 fragments (B-operand: K=y=quad*8+e, 16-col = n=l15)
    bf16x8 fr[4];
#pragma unroll
    for (int xi = 0; xi < 4; ++xi) {
        union { bf16x8 v; unsigned short s[8]; } f;
#pragma unroll
        for (int e = 0; e < 8; ++e)
            f.s[e] = f2bf(acc[xi][e >> 2][e & 3] + ao);
        fr[xi] = f.v;
    }

    // A-operand frags (both stages): A[row=l15][k=quad*8+j] = C[row][pos]
    union { bf16x8 v; unsigned short s[8]; } af0, af1;
    af0.v = *(const bf16x8*)(Cbf + l15 * 32 + quad * 8);
    af1.v = *(const bf16x8*)(Cbf + (16 + l15) * 32 + quad * 8);

    const f32x4 zero = {0.f, 0.f, 0.f, 0.f};

    // ---- stage 1b: MFMAs (transient acc) -> LDS scatter ----
#pragma unroll
    for (int fh = 0; fh < 2; ++fh) {
        f32x4 dd[4];
#pragma unroll
        for (int xi = 0; xi < 4; ++xi)
            dd[xi] = __builtin_amdgcn_mfma_f32_16x16x32_bf16(
                fh ? af1.v : af0.v, fr[xi], zero, 0, 0, 0);
        // scatter: T[f1][n=l15][x-chunk w], rows f1 = fh*16+quad*4+r
#pragma unroll
        for (int r = 0; r < 4; ++r) {
            const int f1 = fh * 16 + quad * 4 + r;
            ushort4 pk;
            pk.x = f2bf(dd[0][r]);
            pk.y = f2bf(dd[1][r]);
            pk.z = f2bf(dd[2][r]);
            pk.w = f2bf(dd[3][r]);
            *(ushort4*)(Tls + f1 * 1280 + l15 * 80 + w * 8) = pk;
        }
    }
    __syncthreads();

    // ---- stage 2: LDS -> MFMA -> scattered stores (T2 entries prefetched) ----
    const size_t obase = (size_t)bc * 262144 + (size_t)m * 16 + (size_t)l15;
#pragma unroll
    for (int i = 0; i < 4; ++i) {
        const int f1 = w * 4 + i;   // stage-1 freq == u (column freq)
        union { int4 q[4]; int2 e[8]; } tt;
        const int4* tp = (const int4*)(T2 + ((f1 * 4 + quad) << 3));
        tt.q[0] = tp[0]; tt.q[1] = tp[1]; tt.q[2] = tp[2]; tt.q[3] = tp[3];
        bf16x8 bfr = *(const bf16x8*)(Tls + f1 * 1280 + l15 * 80 + quad * 16);
#pragma unroll
        for (int uh = 0; uh < 2; ++uh) {
            f32x4 d2 = __builtin_amdgcn_mfma_f32_16x16x32_bf16(
                uh ? af1.v : af0.v, bfr, zero, 0, 0, 0);
#pragma unroll
            for (int r = 0; r < 4; ++r) {
                int2 ks = tt.e[uh * 4 + r];   // {k, scale} for f2 = uh*16+quad*4+r
                out[obase + (size_t)ks.x * 256] = d2[r] * __int_as_float(ks.y);
            }
        }
    }
}

extern "C" void kernel_launch(void* const* d_in, const int* in_sizes, int n_in,
                              void* d_out, int out_size, void* d_ws, size_t ws_size,
                              hipStream_t stream) {
    const float* rgb     = (const float*)d_in[0];  // (32,3,512,512)
    const float* kern    = (const float*)d_in[1];  // (1024,32,32)
    const float* factors = (const float*)d_in[2];  // (1024,)
    float* out = (float*)d_out;                    // (32,3072,16,16)

    unsigned short* Cbf = (unsigned short*)d_ws;          // 2 KB
    int2* T2 = (int2*)((char*)d_ws + 8192);               // 8 KB

    setup_kernel<<<4, 256, 0, stream>>>(kern, factors, Cbf, T2);
    dct_fused<<<1536, 512, 0, stream>>>(rgb, Cbf, T2, out);
}

// Round 4
// 204.436 us; speedup vs baseline: 1.2876x; 1.0290x over previous
//
#include <hip/hip_runtime.h>
#include <math.h>

// DCT encoder, separable form. kernels[k] = outer(cv_k, cu_k) with
// cv[i]=cos((2i+1)v pi/64) on ROWS (i), cu[j] on COLUMNS (j)  [meshgrid 'xy'].
// Stage1 contracts y=cols with freq f1==u; stage2 contracts x=rows with f2==v.
// R8 = R5/R7 channel-split structure (the only one with ideal WRITE=103MB) plus
// two anti-serialization mechanisms the compiler can't undo:
//  - forced-MLP loads: asm "+v" keep-alive fences on f32x4 buffers, two plane
//    buffers double-buffered (issue R, issue G, fence R, FMA R, issue B,
//    fence G, FMA G, fence B, FMA B) -> ~16-24 loads in flight per wave.
//    R7 showed the compiler otherwise register-minimizes to VGPR=36 / ~2 deep.
//    __launch_bounds__(512,4): VGPR cap 128, 2 blocks/CU, 1536 blocks = 3 clean
//    rounds (R5 vs R7 proved occupancy is not the binding constraint).
//  - T2 {k,scale} table staged to LDS at block start: stage-2 reads it via
//    ds_read_b128 (lgkmcnt), so NO vmcnt waits exist in stage 2 -> the 32
//    scattered stores per thread stream without being drained once per
//    iteration by T2-load vmcnt waits (vmcnt counts stores on CDNA).

typedef __bf16 bf16x8 __attribute__((ext_vector_type(8)));
typedef float  f32x4  __attribute__((ext_vector_type(4)));

#define PI_F 3.14159265358979323846f

#define KEEP8(B) asm volatile("" : "+v"(B[0]), "+v"(B[1]), "+v"(B[2]), "+v"(B[3]), \
                                   "+v"(B[4]), "+v"(B[5]), "+v"(B[6]), "+v"(B[7]))

__device__ __forceinline__ unsigned short f2bf(float f) {
    union { float f; unsigned u; } v; v.f = f;
    unsigned u = v.u;
    u += 0x7fffu + ((u >> 16) & 1u);   // round-to-nearest-even
    return (unsigned short)(u >> 16);
}

// ---- K0: cos table (bf16) + fused {k, scale} table --------------------------
// kern[k][i][j] = cos((2j+1)u pi/64) * cos((2i+1)v pi/64), k sorted by |(v,u)|.
// v from K[1][0]/K[0][0] = 4cos^2(v pi/64)-3; u from K[0][1]/K[0][0].
// T2r layout: [(u*4 + quad)*8 + uh*4 + r] where v = uh*16 + quad*4 + r,
// so stage-2's (f1=u, quad) thread reads its 8 entries as one 64B run.
__global__ __launch_bounds__(256) void setup_kernel(const float* __restrict__ kern,
                                                    const float* __restrict__ factors,
                                                    unsigned short* __restrict__ Cbf,
                                                    int2* __restrict__ T2) {
    int k = blockIdx.x * 256 + threadIdx.x;   // 0..1023
    int i = k & 31, t = k >> 5;
    Cbf[k] = f2bf(cosf((float)((2 * i + 1) * t) * (PI_F / 64.f)));

    float k00 = kern[(size_t)k * 1024];              // cv[0]*cu[0] > 0 always
    float rv  = kern[(size_t)k * 1024 + 32] / k00;   // -> v
    float ru  = kern[(size_t)k * 1024 + 1]  / k00;   // -> u
    float cv2 = fminf(fmaxf((rv + 3.f) * 0.25f, 0.f), 1.f);
    float cu2 = fminf(fmaxf((ru + 3.f) * 0.25f, 0.f), 1.f);
    int v = __float2int_rn(acosf(sqrtf(cv2)) * (64.f / PI_F));
    int u = __float2int_rn(acosf(sqrtf(cu2)) * (64.f / PI_F));
    float s = factors[k] * (2.f / 32.f);
    int vq = (v >> 2) & 3, vh = v >> 4, vr = v & 3;
    T2[(u * 4 + vq) * 8 + vh * 4 + vr] = make_int2(k, __float_as_int(s));
}

// ---- fused kernel: one block per (b, m, c) strip of 16 DCT blocks -----------
// Stage1: T[f1][n][x] = sum_y C[f1][y] * ycbcr[c][m*32+x][n*32+y]   (MFMA, K=32)
// Stage2: out[bc][k(f2,f1)][m*16+n] = s * sum_x C[f2][x] * T[f1][n][x]
// LDS: T buffer 40 KB (row 80B = 32 bf16 + pad, f1-stride 1280B) + T2 copy 8 KB.
__global__ __launch_bounds__(512, 4) void dct_fused(const float* __restrict__ rgb,
                                                    const unsigned short* __restrict__ Cbf,
                                                    const int2* __restrict__ T2,
                                                    float* __restrict__ out) {
    __shared__ __align__(16) unsigned char Tls[32 * 1280];   // 40 KB
    __shared__ __align__(16) unsigned char T2ls[8192];       // 8 KB

    const int tid  = threadIdx.x;
    const int lane = tid & 63;
    const int w    = tid >> 6;        // wave 0..7, owns x = w*4..w*4+3
    const int quad = lane >> 4;
    const int l15  = lane & 15;
    // blockIdx decode: g = bc*16 + loc, bc = b*3 + c (c at stride 16 -> same XCD
    // for a strip's 3 channel-blocks), loc -> m with the g<->g+8 pair swizzle
    // so m=2t / 2t+1 half-lines merge to one 128B line in that XCD's L2.
    const int g    = blockIdx.x;
    const int bc   = g >> 4;          // 0..95
    const int b    = bc / 3;
    const int c    = bc - b * 3;
    const int loc  = g & 15;
    const int m    = ((loc & 7) << 1) | (loc >> 3);

    // T2 -> LDS staging load (oldest VMEM op; ds_write placed after plane issues)
    int4 t2chunk = *((const int4*)T2 + tid);

    // A-operand frags (both stages): A[row=l15][k=quad*8+j] = C[row][pos]
    union { bf16x8 v; unsigned short s[8]; } af0, af1;
    af0.v = *(const bf16x8*)(Cbf + l15 * 32 + quad * 8);
    af1.v = *(const bf16x8*)(Cbf + (16 + l15) * 32 + quad * 8);

    // channel conversion folded to one dot product: val = ar*R + ag*G + ab*B + ao
    float ar, ag, ab, ao;
    if (c == 0)      { ar =  0.598f;     ag =  1.174f;     ab =  0.228f;     ao = -1.f; }
    else if (c == 1) { ar = -0.337272f;  ag = -0.662136f;  ab =  0.999408f;  ao =  0.f; }
    else             { ar =  0.999626f;  ag = -0.837062f;  ab = -0.162564f;  ao =  0.f; }

    // ---- stage 1a: double-buffered plane passes with forced-MLP fences -----
    // This thread's 32 input elems: rows x = w*4+xi, cols l15*32+quad*8+e.
    const float* prow = rgb + (size_t)b * 786432
                            + (size_t)(m * 32 + w * 4) * 512
                            + (size_t)l15 * 32 + (size_t)quad * 8;
    f32x4 bufA[8], bufB[8];
    f32x4 acc[4][2];

    // issue all 8 R loads
#pragma unroll
    for (int xi = 0; xi < 4; ++xi) {
        bufA[2 * xi]     = *(const f32x4*)(prow + (size_t)xi * 512);
        bufA[2 * xi + 1] = *(const f32x4*)(prow + (size_t)xi * 512 + 4);
    }
    // issue all 8 G loads
#pragma unroll
    for (int xi = 0; xi < 4; ++xi) {
        bufB[2 * xi]     = *(const f32x4*)(prow + 262144 + (size_t)xi * 512);
        bufB[2 * xi + 1] = *(const f32x4*)(prow + 262144 + (size_t)xi * 512 + 4);
    }
    // park T2 chunk into LDS (waits only on the oldest load; R/G stay in flight)
    *(int4*)(T2ls + tid * 16) = t2chunk;

    KEEP8(bufA);   // R complete; G in flight
#pragma unroll
    for (int xi = 0; xi < 4; ++xi)
#pragma unroll
        for (int h = 0; h < 2; ++h) {
            acc[xi][h][0] = ar * bufA[2 * xi + h][0];
            acc[xi][h][1] = ar * bufA[2 * xi + h][1];
            acc[xi][h][2] = ar * bufA[2 * xi + h][2];
            acc[xi][h][3] = ar * bufA[2 * xi + h][3];
        }
    // issue all 8 B loads (reuse bufA)
#pragma unroll
    for (int xi = 0; xi < 4; ++xi) {
        bufA[2 * xi]     = *(const f32x4*)(prow + 524288 + (size_t)xi * 512);
        bufA[2 * xi + 1] = *(const f32x4*)(prow + 524288 + (size_t)xi * 512 + 4);
    }
    KEEP8(bufB);   // G complete; B in flight
#pragma unroll
    for (int xi = 0; xi < 4; ++xi)
#pragma unroll
        for (int h = 0; h < 2; ++h) {
            acc[xi][h][0] += ag * bufB[2 * xi + h][0];
            acc[xi][h][1] += ag * bufB[2 * xi + h][1];
            acc[xi][h][2] += ag * bufB[2 * xi + h][2];
            acc[xi][h][3] += ag * bufB[2 * xi + h][3];
        }
    KEEP8(bufA);   // B complete
#pragma unroll
    for (int xi = 0; xi < 4; ++xi)
#pragma unroll
        for (int h = 0; h < 2; ++h) {
            acc[xi][h][0] += ab * bufA[2 * xi + h][0];
            acc[xi][h][1] += ab * bufA[2 * xi + h][1];
            acc[xi][h][2] += ab * bufA[2 * xi + h][2];
            acc[xi][h][3] += ab * bufA[2 * xi + h][3];
        }

    // pack to bf16 fragments (B-operand: K=y=quad*8+e, 16-col = n=l15)
    bf16x8 fr[4];
#pragma unroll
    for (int xi = 0; xi < 4; ++xi) {
        union { bf16x8 v; unsigned short s[8]; } f;
#pragma unroll
        for (int e = 0; e < 8; ++e)
            f.s[e] = f2bf(acc[xi][e >> 2][e & 3] + ao);
        fr[xi] = f.v;
    }

    const f32x4 zero = {0.f, 0.f, 0.f, 0.f};

    // ---- stage 1b: MFMAs (transient acc) -> LDS scatter ----
#pragma unroll
    for (int fh = 0; fh < 2; ++fh) {
        f32x4 dd[4];
#pragma unroll
        for (int xi = 0; xi < 4; ++xi)
            dd[xi] = __builtin_amdgcn_mfma_f32_16x16x32_bf16(
                fh ? af1.v : af0.v, fr[xi], zero, 0, 0, 0);
        // scatter: T[f1][n=l15][x-chunk w], rows f1 = fh*16+quad*4+r
#pragma unroll
        for (int r = 0; r < 4; ++r) {
            const int f1 = fh * 16 + quad * 4 + r;
            ushort4 pk;
            pk.x = f2bf(dd[0][r]);
            pk.y = f2bf(dd[1][r]);
            pk.z = f2bf(dd[2][r]);
            pk.w = f2bf(dd[3][r]);
            *(ushort4*)(Tls + f1 * 1280 + l15 * 80 + w * 8) = pk;
        }
    }
    __syncthreads();   // also publishes T2ls

    // ---- stage 2: LDS -> MFMA -> scattered stores (T2 from LDS: no vmcnt) ----
    const size_t obase = (size_t)bc * 262144 + (size_t)m * 16 + (size_t)l15;
#pragma unroll
    for (int i = 0; i < 4; ++i) {
        const int f1 = w * 4 + i;   // stage-1 freq == u (column freq)
        union { int4 q[4]; int2 e[8]; } tt;
        const unsigned char* tp = T2ls + (f1 * 4 + quad) * 64;
        tt.q[0] = *(const int4*)(tp);
        tt.q[1] = *(const int4*)(tp + 16);
        tt.q[2] = *(const int4*)(tp + 32);
        tt.q[3] = *(const int4*)(tp + 48);
        bf16x8 bfr = *(const bf16x8*)(Tls + f1 * 1280 + l15 * 80 + quad * 16);
#pragma unroll
        for (int uh = 0; uh < 2; ++uh) {
            f32x4 d2 = __builtin_amdgcn_mfma_f32_16x16x32_bf16(
                uh ? af1.v : af0.v, bfr, zero, 0, 0, 0);
#pragma unroll
            for (int r = 0; r < 4; ++r) {
                int2 ks = tt.e[uh * 4 + r];   // {k, scale} for f2 = uh*16+quad*4+r
                out[obase + (size_t)ks.x * 256] = d2[r] * __int_as_float(ks.y);
            }
        }
    }
}

extern "C" void kernel_launch(void* const* d_in, const int* in_sizes, int n_in,
                              void* d_out, int out_size, void* d_ws, size_t ws_size,
                              hipStream_t stream) {
    const float* rgb     = (const float*)d_in[0];  // (32,3,512,512)
    const float* kern    = (const float*)d_in[1];  // (1024,32,32)
    const float* factors = (const float*)d_in[2];  // (1024,)
    float* out = (float*)d_out;                    // (32,3072,16,16)

    unsigned short* Cbf = (unsigned short*)d_ws;          // 2 KB
    int2* T2 = (int2*)((char*)d_ws + 8192);               // 8 KB

    setup_kernel<<<4, 256, 0, stream>>>(kern, factors, Cbf, T2);
    dct_fused<<<1536, 512, 0, stream>>>(rgb, Cbf, T2, out);
}